// Round 10
// baseline (66.250 us; speedup 1.0000x reference)
//
#include <hip/hip_runtime.h>
#include <hip/hip_bf16.h>

#define EPS 1e-5f
#define SLOPE 0.01f

typedef __attribute__((ext_vector_type(8))) short bfrag8;   // 8 bf16 (4 VGPRs)
typedef __attribute__((ext_vector_type(4))) float f32x4;

#define AS1 __attribute__((address_space(1)))
#define AS3 __attribute__((address_space(3)))

// ---- workspace byte offsets ----
#define WS_SIM_OFF   0u          // [1024][16] f32
#define WS_S_OFF     65536u      // [1024][16] f32
#define WS_WVS_OFF   131072u     // [2048][16] f32, transposed [c][n]
#define WS_BVS_OFF   262144u     // [16] f32
#define WS_OUT0_OFF  262208u     // [1024][2048] f32 partial (k 0..1023)
#define WS_OUT1_OFF  8650816u    // [1024][2048] f32 partial (k 1024..2047)
#define WS_AIMG_OFF  17039424u   // bf16 A image, swizzle-baked: [src2][mt8][ktg32][p1024]x16B = 8,388,608 B
#define WS_BIMG_OFF  25428032u   // bf16 B image, swizzle-baked: [nt16][ktg32][p1024]x16B = 8,388,608 B

// round-to-nearest-even fp32 -> bf16
__device__ __forceinline__ unsigned short f2bf(float f) {
    union { float f; unsigned int u; } x; x.f = f;
    unsigned int r = (x.u + 0x7FFFu + ((x.u >> 16) & 1u)) >> 16;
    return (unsigned short)r;
}
__device__ __forceinline__ uint4 pack8(const float4& a, const float4& b) {
    uint4 r;
    r.x = (unsigned)f2bf(a.x) | ((unsigned)f2bf(a.y) << 16);
    r.y = (unsigned)f2bf(a.z) | ((unsigned)f2bf(a.w) << 16);
    r.z = (unsigned)f2bf(b.x) | ((unsigned)f2bf(b.y) << 16);
    r.w = (unsigned)f2bf(b.z) | ((unsigned)f2bf(b.w) << 16);
    return r;
}

// ---------------- kernel 0: prep — swizzle-baked bf16 images (128-wide tiles) + WvS + bvS ----------------
// Granule p (16 B) of a 128x64 k-tile: row = p>>3, slot g = p&7 holds k-granule
// gk = g ^ (row&7)  (T2 XOR baked at build; ds_read applies the same XOR — verified r8/r9).
#define PREP_A    524288                    // 2*8*32*1024
#define PREP_B2   (PREP_A + 524288)         // 16*32*1024
#define PREP_WVSE (PREP_B2 + 32768)
#define PREP_END  (PREP_WVSE + 16)

__global__ __launch_bounds__(256) void prep_kernel(
        const float* __restrict__ qin, const float* __restrict__ kvin,
        const float* __restrict__ Wq, const float* __restrict__ Wkv,
        const float* __restrict__ bkv, unsigned char* __restrict__ ws) {
    int gid = blockIdx.x * 256 + threadIdx.x;
    if (gid < PREP_A) {
        int p   = gid & 1023;
        int ktg = (gid >> 10) & 31;
        int mt  = (gid >> 15) & 7;
        int s2  = gid >> 18;                   // 0 = q_input, 1 = kv_input
        int rit = p >> 3;                      // row in tile 0..127
        int gk  = (p & 7) ^ (rit & 7);
        int row = mt * 128 + rit;
        int k   = ktg * 64 + gk * 8;
        const float* src = (s2 ? kvin : qin) + (size_t)row * 2048 + k;
        float4 v0 = *(const float4*)src;
        float4 v1 = *(const float4*)(src + 4);
        *(uint4*)(ws + WS_AIMG_OFF + (size_t)gid * 16) = pack8(v0, v1);
    } else if (gid < PREP_B2) {
        int g2  = gid - PREP_A;
        int p   = g2 & 1023;
        int ktg = (g2 >> 10) & 31;
        int nt  = g2 >> 15;                    // 0..15
        int cit = p >> 3;                      // col in tile 0..127
        int gk  = (p & 7) ^ (cit & 7);
        int col = nt * 128 + cit;
        int k   = ktg * 64 + gk * 8;
        const float* wrow;
        if (col < 1024) wrow = Wq + (size_t)col * 2048;
        else {
            int c2 = col - 1024;
            wrow = Wkv + (size_t)(((c2 >> 6) << 7) + (c2 & 63)) * 2048;
        }
        float4 v0 = *(const float4*)(wrow + k);
        float4 v1 = *(const float4*)(wrow + k + 4);
        *(uint4*)(ws + WS_BIMG_OFF + (size_t)g2 * 16) = pack8(v0, v1);
    } else if (gid < PREP_WVSE) {
        int g2 = gid - PREP_B2;
        int n = g2 >> 11, c = g2 & 2047;
        const float* base = Wkv + (size_t)(n * 128 + 64) * 2048 + c;
        float s = 0.f;
        #pragma unroll 8
        for (int d = 0; d < 64; ++d) s += base[(size_t)d * 2048];
        ((float*)(ws + WS_WVS_OFF))[c * 16 + n] = s;
    } else if (gid < PREP_END) {
        int n = gid - PREP_WVSE;
        float b = 0.f;
        #pragma unroll
        for (int d = 0; d < 64; ++d) b += bkv[n * 128 + 64 + d];
        ((float*)(ws + WS_BVS_OFF))[n] = b;
    }
}

// ---------------- kernel 1: projection GEMM, 128x128 tile, wave C=64x64 (m97 microtile) ----------------
// grid (x=nt 16, y=mt 8, z=kz 2) = 256 blocks (1/CU). 4 waves (wr,wc in {0,1}).
// 4-buffer LDS (128 KB), depth-3 prefetch, steady-state s_waitcnt vmcnt(16)
// (3 stages x 8 DMAs in flight; only the tile needed at the barrier is forced complete).
// K-split partials are fp32-summed in sim_s BEFORE q*k pairing (bilinear-exact).
__global__ __launch_bounds__(256) void gemm_qk_kernel(unsigned char* __restrict__ ws) {
    __shared__ alignas(16) unsigned short LA[4][8192];   // 4 x 16 KB
    __shared__ alignas(16) unsigned short LB[4][8192];

    const int t = threadIdx.x;
    const int w = t >> 6, l = t & 63;
    const int nt = blockIdx.x, mt = blockIdx.y, kz = blockIdx.z;
    const int wr = w >> 1, wc = w & 1;
    const int lrow = l & 15, lhi = l >> 4;

    const unsigned char* aBase = ws + WS_AIMG_OFF
        + (size_t)((nt >= 8) ? 4194304u : 0u) + (size_t)mt * 524288u
        + (size_t)kz * 262144u;                           // 16 k-tiles of 16 KB
    const unsigned char* bBase = ws + WS_BIMG_OFF
        + (size_t)nt * 524288u + (size_t)kz * 262144u;
    float* Out = (float*)(ws + (kz ? WS_OUT1_OFF : WS_OUT0_OFF));

    // swizzled ds_read byte offsets (slot = s ^ (row&7), s = ks*4+lhi)
    int offA[2][4], offB[2][4];
    #pragma unroll
    for (int ks = 0; ks < 2; ++ks)
        #pragma unroll
        for (int i = 0; i < 4; ++i) {
            int rA = wr * 64 + i * 16 + lrow;
            int rB = wc * 64 + i * 16 + lrow;
            offA[ks][i] = rA * 128 + (((ks * 4 + lhi) ^ (rA & 7)) << 4);
            offB[ks][i] = rB * 128 + (((ks * 4 + lhi) ^ (rB & 7)) << 4);
        }

    f32x4 acc[4][4];
    #pragma unroll
    for (int mi = 0; mi < 4; ++mi)
        #pragma unroll
        for (int ni = 0; ni < 4; ++ni) acc[mi][ni] = (f32x4)0.f;

#define STAGE(kt_, buf_) do {                                                        \
    const unsigned char* _as = aBase + (size_t)(kt_) * 16384;                        \
    const unsigned char* _bs = bBase + (size_t)(kt_) * 16384;                        \
    unsigned char* _ad = ((unsigned char*)&LA[0][0]) + (size_t)(buf_) * 16384;       \
    unsigned char* _bd = ((unsigned char*)&LB[0][0]) + (size_t)(buf_) * 16384;       \
    _Pragma("unroll")                                                                \
    for (int _j = 0; _j < 4; ++_j) {                                                 \
        int _p = _j * 256 + t;                                                       \
        __builtin_amdgcn_global_load_lds(                                            \
            (const AS1 unsigned int*)(const void*)(_as + _p * 16),                   \
            (AS3 unsigned int*)(void*)(_ad + _p * 16), 16, 0, 0);                    \
        __builtin_amdgcn_global_load_lds(                                            \
            (const AS1 unsigned int*)(const void*)(_bs + _p * 16),                   \
            (AS3 unsigned int*)(void*)(_bd + _p * 16), 16, 0, 0);                    \
    } } while (0)

    // ---- prologue: stage 0,1,2; complete 0 only (16 = 2 stages left in flight) ----
    STAGE(0, 0);
    STAGE(1, 1);
    STAGE(2, 2);
    asm volatile("s_waitcnt vmcnt(16)" ::: "memory");
    __builtin_amdgcn_sched_barrier(0);
    __builtin_amdgcn_s_barrier();
    __builtin_amdgcn_sched_barrier(0);

    for (int kt = 0; kt < 16; ++kt) {
        const int cur = kt & 3;
        // issue stage kt+3 first (overlaps this iter's compute; WAR-safe: buffer
        // (kt+3)&3 == (kt-1)&3 was fully read before the end-of-(kt-1) barrier)
        if (kt <= 12) STAGE(kt + 3, (kt + 3) & 3);
        const char* la = (const char*)&LA[0][0] + (size_t)cur * 16384;
        const char* lb = (const char*)&LB[0][0] + (size_t)cur * 16384;
        #pragma unroll
        for (int ks = 0; ks < 2; ++ks) {
            bfrag8 fa[4], fb[4];
            #pragma unroll
            for (int i = 0; i < 4; ++i) {
                fa[i] = *(const bfrag8*)(la + offA[ks][i]);
                fb[i] = *(const bfrag8*)(lb + offB[ks][i]);
            }
            #pragma unroll
            for (int mi = 0; mi < 4; ++mi)
                #pragma unroll
                for (int ni = 0; ni < 4; ++ni)
                    acc[mi][ni] = __builtin_amdgcn_mfma_f32_16x16x32_bf16(
                        fa[mi], fb[ni], acc[mi][ni], 0, 0, 0);
        }
        // counted drain: force only tile kt+1 complete; leave kt+2, kt+3 in flight
        if (kt <= 12)      asm volatile("s_waitcnt vmcnt(16)" ::: "memory");
        else if (kt == 13) asm volatile("s_waitcnt vmcnt(8)"  ::: "memory");
        else               asm volatile("s_waitcnt vmcnt(0)"  ::: "memory");
        __builtin_amdgcn_sched_barrier(0);
        __builtin_amdgcn_s_barrier();
        __builtin_amdgcn_sched_barrier(0);
    }
#undef STAGE

    // epilogue: store fp32 partial (bias + pairing in sim_s)
    #pragma unroll
    for (int mi = 0; mi < 4; ++mi)
        #pragma unroll
        for (int ni = 0; ni < 4; ++ni) {
            int col = nt * 128 + wc * 64 + ni * 16 + lrow;
            #pragma unroll
            for (int r = 0; r < 4; ++r) {
                int row = mt * 128 + wr * 64 + mi * 16 + lhi * 4 + r;
                Out[(size_t)row * 2048 + col] = acc[mi][ni][r];
            }
        }
}

// ---------------- kernel 2: sim[b,h] = (q+bq)·(k+bk) ; S[b][n] = kv·WvS + bvS ----------------
__global__ __launch_bounds__(256) void sim_s_kernel(
        const float* __restrict__ bq, const float* __restrict__ bkv,
        const float* __restrict__ kvin, unsigned char* __restrict__ ws) {
    int b = blockIdx.x, t = threadIdx.x;
    int w = t >> 6, l = t & 63;
    // --- sim: sum K-split partials (exact), add fp32 bias, pair, reduce over d ---
    {
        const float* o0 = (const float*)(ws + WS_OUT0_OFF) + (size_t)b * 2048;
        const float* o1 = (const float*)(ws + WS_OUT1_OFF) + (size_t)b * 2048;
        float* sim = (float*)(ws + WS_SIM_OFF);
        #pragma unroll
        for (int hh = 0; hh < 4; ++hh) {
            int h = w * 4 + hh;
            float qv = o0[h * 64 + l]        + o1[h * 64 + l]        + bq[h * 64 + l];
            float kv = o0[1024 + h * 64 + l] + o1[1024 + h * 64 + l] + bkv[h * 128 + l];
            float p = qv * kv;
            p += __shfl_xor(p, 1);  p += __shfl_xor(p, 2);
            p += __shfl_xor(p, 4);  p += __shfl_xor(p, 8);
            p += __shfl_xor(p, 16); p += __shfl_xor(p, 32);
            if (l == 0) sim[b * 16 + h] = p;
        }
    }
    // --- S ---
    __shared__ float SW[4][16];
    int n = t & 15, g = t >> 4;
    const float* kvrow = kvin + (size_t)b * 2048;
    const float* wv = (const float*)(ws + WS_WVS_OFF);
    float p = 0.f;
    #pragma unroll 4
    for (int tt = 0; tt < 128; ++tt) {
        int c = g + (tt << 4);
        p = fmaf(kvrow[c], wv[c * 16 + n], p);
    }
    p += __shfl_xor(p, 16);
    p += __shfl_xor(p, 32);
    if (l < 16) SW[w][n] = p;
    __syncthreads();
    if (t < 16) {
        float sv = SW[0][t] + SW[1][t] + SW[2][t] + SW[3][t]
                 + ((const float*)(ws + WS_BVS_OFF))[t];
        ((float*)(ws + WS_S_OFF))[b * 16 + t] = sv;
    }
}

// ---------------- kernel 3: softmax, A-reduce, pooled, leaky, batchnorm, output ----------------
__global__ __launch_bounds__(1024) void final_kernel(
        const float* __restrict__ bn_w, const float* __restrict__ bn_b,
        const float* __restrict__ Wo, const float* __restrict__ bo,
        const unsigned char* __restrict__ ws, float* __restrict__ out) {
    int t = threadIdx.x;
    int w = t >> 6;
    int l = t & 63;
    __shared__ float Aw[16][16];
    __shared__ float Af[4][16];
    __shared__ float SWs[16][8];
    __shared__ float FS[8];
    __shared__ float sc[4], sh[4];

    float a16[16];
    {
        const float* srow = (const float*)(ws + WS_SIM_OFF) + (size_t)t * 16;
        float4 v0 = *(const float4*)(srow + 0);
        float4 v1 = *(const float4*)(srow + 4);
        float4 v2 = *(const float4*)(srow + 8);
        float4 v3 = *(const float4*)(srow + 12);
        a16[0]=v0.x; a16[1]=v0.y; a16[2]=v0.z; a16[3]=v0.w;
        a16[4]=v1.x; a16[5]=v1.y; a16[6]=v1.z; a16[7]=v1.w;
        a16[8]=v2.x; a16[9]=v2.y; a16[10]=v2.z; a16[11]=v2.w;
        a16[12]=v3.x; a16[13]=v3.y; a16[14]=v3.z; a16[15]=v3.w;
        float m = a16[0];
        #pragma unroll
        for (int n = 1; n < 16; ++n) m = fmaxf(m, a16[n]);
        float den = 0.f;
        #pragma unroll
        for (int n = 0; n < 16; ++n) { a16[n] = expf(a16[n] - m); den += a16[n]; }
        float inv = 1.f / den;
        #pragma unroll
        for (int n = 0; n < 16; ++n) a16[n] *= inv;
    }
    #pragma unroll
    for (int n = 0; n < 16; ++n) {
        float p = a16[n];
        p += __shfl_xor(p, 1);  p += __shfl_xor(p, 2);
        p += __shfl_xor(p, 4);  p += __shfl_xor(p, 8);
        p += __shfl_xor(p, 16); p += __shfl_xor(p, 32);
        a16[n] = p;
    }
    if (l == 0) {
        #pragma unroll
        for (int n = 0; n < 16; ++n) Aw[w][n] = a16[n];
    }
    __syncthreads();
    if (t < 64) {
        int f = t >> 4, n = t & 15;
        Af[f][n] = Aw[4*f][n] + Aw[4*f+1][n] + Aw[4*f+2][n] + Aw[4*f+3][n];
    }
    __syncthreads();

    float sv[16];
    {
        const float* srow = (const float*)(ws + WS_S_OFF) + (size_t)t * 16;
        float4 v0 = *(const float4*)(srow + 0);
        float4 v1 = *(const float4*)(srow + 4);
        float4 v2 = *(const float4*)(srow + 8);
        float4 v3 = *(const float4*)(srow + 12);
        sv[0]=v0.x; sv[1]=v0.y; sv[2]=v0.z; sv[3]=v0.w;
        sv[4]=v1.x; sv[5]=v1.y; sv[6]=v1.z; sv[7]=v1.w;
        sv[8]=v2.x; sv[9]=v2.y; sv[10]=v2.z; sv[11]=v2.w;
        sv[12]=v3.x; sv[13]=v3.y; sv[14]=v3.z; sv[15]=v3.w;
    }
    float x[4];
    #pragma unroll
    for (int f = 0; f < 4; ++f) {
        float p = 0.f;
        #pragma unroll
        for (int n = 0; n < 16; ++n) p = fmaf(Af[f][n], sv[n], p);
        p *= (1.f / 16384.f);
        x[f] = (p >= 0.f) ? p : SLOPE * p;
    }

    float st[8];
    #pragma unroll
    for (int f = 0; f < 4; ++f) { st[f] = x[f]; st[4 + f] = x[f] * x[f]; }
    #pragma unroll
    for (int j = 0; j < 8; ++j) {
        float p = st[j];
        p += __shfl_xor(p, 1);  p += __shfl_xor(p, 2);
        p += __shfl_xor(p, 4);  p += __shfl_xor(p, 8);
        p += __shfl_xor(p, 16); p += __shfl_xor(p, 32);
        st[j] = p;
    }
    if (l == 0) {
        #pragma unroll
        for (int j = 0; j < 8; ++j) SWs[w][j] = st[j];
    }
    __syncthreads();
    if (t < 8) {
        float p = 0.f;
        #pragma unroll
        for (int ww = 0; ww < 16; ++ww) p += SWs[ww][t];
        FS[t] = p;
    }
    __syncthreads();
    if (t < 4) {
        float mean = FS[t] * (1.f / 1024.f);
        float var  = FS[4 + t] * (1.f / 1024.f) - mean * mean;
        float s = bn_w[t] / sqrtf(var + EPS);
        sc[t] = s;
        sh[t] = bn_b[t] - mean * s;
    }
    __syncthreads();

    float o0 = bo[0], o1 = bo[1];
    #pragma unroll
    for (int f = 0; f < 4; ++f) {
        float xh = x[f] * sc[f] + sh[f];
        o0 = fmaf(xh, Wo[f], o0);
        o1 = fmaf(xh, Wo[4 + f], o1);
    }
    *(float2*)(out + (size_t)t * 2) = make_float2(o0, o1);
}

// ---------------- launch ----------------
extern "C" void kernel_launch(void* const* d_in, const int* in_sizes, int n_in,
                              void* d_out, int out_size, void* d_ws, size_t ws_size,
                              hipStream_t stream) {
    const float* q_input  = (const float*)d_in[0];
    const float* kv_input = (const float*)d_in[1];
    const float* Wq   = (const float*)d_in[2];
    const float* bq   = (const float*)d_in[3];
    const float* Wkv  = (const float*)d_in[4];
    const float* bkv  = (const float*)d_in[5];
    const float* bn_w = (const float*)d_in[6];
    const float* bn_b = (const float*)d_in[7];
    const float* Wo   = (const float*)d_in[8];
    const float* bo   = (const float*)d_in[9];
    float* out = (float*)d_out;
    unsigned char* ws = (unsigned char*)d_ws;

    hipLaunchKernelGGL(prep_kernel, dim3((PREP_END + 255) / 256), dim3(256), 0, stream,
                       q_input, kv_input, Wq, Wkv, bkv, ws);
    hipLaunchKernelGGL(gemm_qk_kernel, dim3(16, 8, 2), dim3(256), 0, stream, ws);
    hipLaunchKernelGGL(sim_s_kernel, dim3(1024), dim3(256), 0, stream,
                       bq, bkv, kv_input, ws);
    hipLaunchKernelGGL(final_kernel, dim3(1), dim3(1024), 0, stream,
                       bn_w, bn_b, Wo, bo, ws, out);
}